// Round 7
// baseline (209.456 us; speedup 1.0000x reference)
//
#include <hip/hip_runtime.h>
#include <math.h>
#include <limits.h>

#define NEV 100000
#define NB 8
#define NSL 32                   // slices per batch
#define SLEV (NEV / NSL)         // 3125 events per slice
#define F32EPS 1.1920929e-7f
#define SCALE 524288.0f          // 2^19 fixed-point for num
#define INV_SCALE (1.0f/524288.0f)

typedef unsigned long long u64;

// ws layout (bytes):
//   0          bins: uint2[8][NEV]                 6,400,000
//   6,400,000  binStart: int[8][33]                1,056
//   6,401,056  tref: float[32]                     128
//   6,401,184  fi0S: u64[16][2048]                 262,144   (atomic-merged plane)
//   6,663,328  fi1S: u64[16][8192]                 1,048,576 (atomic-merged plane)
//   7,711,904  histG: int[256][4][32]              131,072
//   7,842,976  mmG:   int[256][4]                  4,096
//   7,847,072  miscP: float[1024]                  4,096
//   7,851,168  ctr:   int                          4
#define OFF_BINSTART 6400000
#define OFF_TREF     6401056
#define OFF_FI0S     6401184
#define OFF_FI1S     6663328
#define OFF_HISTG    7711904
#define OFF_MMG      7842976
#define OFF_MISCP    7847072
#define OFF_CTR      7851168

#define MISC_BLOCKS 1024

__device__ __forceinline__ void lds_add64(u64* p, u64 v) {
    __hip_atomic_fetch_add(p, v, __ATOMIC_RELAXED, __HIP_MEMORY_SCOPE_WORKGROUP);
}
__device__ __forceinline__ int lds_add32(int* p, int v) {
    return __hip_atomic_fetch_add(p, v, __ATOMIC_RELAXED, __HIP_MEMORY_SCOPE_WORKGROUP);
}

// fast z^0.45 for z > 0: v_log_f32 (log2) + v_mul + v_exp_f32 (2^x) — 3 ops.
// (__powf lowers to the full OCML pow path; R6 confirmed −14 us from this.)
__device__ __forceinline__ float pow045(float z) {
    return __builtin_amdgcn_exp2f(0.45f * __builtin_amdgcn_logf(z));
}

// =============== pass 1: hist (blocks 0-255) PARALLEL misc (blocks 256-1279) ===============
__global__ __launch_bounds__(256) void k_front(
    const int* __restrict__ ys, const int* __restrict__ ps,
    const float* __restrict__ params, int nP,
    const float* __restrict__ f0, const float* __restrict__ f1,
    const float* __restrict__ f2, const float* __restrict__ f3,
    int* __restrict__ histG, int* __restrict__ mmG, float* __restrict__ miscP,
    u64* __restrict__ fi0S, u64* __restrict__ fi1S, int* __restrict__ ctr) {
    int tid = threadIdx.x;
    int bid = blockIdx.x;
    __shared__ int hist[4][32];
    __shared__ int mm[4];
    __shared__ float red[4];

    if (bid < 256) {
        // ---- histogram + minmax for (slice, batch) ----
        int b = bid & 7;
        int sl = bid >> 3;
        int w = tid >> 6, lane = tid & 63;
        const int* yb = ys + b * NEV + sl * SLEV;
        const int* pb = ps + b * NEV + sl * SLEV;

        if (tid < 128) hist[tid >> 5][tid & 31] = 0;
        if (tid == 0) { mm[0] = INT_MAX; mm[1] = -1; mm[2] = INT_MAX; mm[3] = -1; }
        __syncthreads();

        int mnP = INT_MAX, mxP = -1, mnN = INT_MAX, mxN = -1;
        int gbase = sl * SLEV;
        for (int i = w * 64 + lane; i < SLEV; i += 256) {
            int p = pb[i];
            int y = yb[i];
            int m = (p == 1) ? 0 : 1;
            lds_add32(&hist[w][m * 16 + (y >> 4)], 1);
            int gi = gbase + i;
            if (m == 0) { mnP = min(mnP, gi); mxP = max(mxP, gi); }
            else        { mnN = min(mnN, gi); mxN = max(mxN, gi); }
        }
        for (int o = 32; o > 0; o >>= 1) {
            mnP = min(mnP, __shfl_down(mnP, o, 64));
            mxP = max(mxP, __shfl_down(mxP, o, 64));
            mnN = min(mnN, __shfl_down(mnN, o, 64));
            mxN = max(mxN, __shfl_down(mxN, o, 64));
        }
        if (lane == 0) {
            atomicMin(&mm[0], mnP); atomicMax(&mm[1], mxP);
            atomicMin(&mm[2], mnN); atomicMax(&mm[3], mxN);
        }
        __syncthreads();
        if (tid < 128) histG[(bid * 4 + (tid >> 5)) * 32 + (tid & 31)] = hist[tid >> 5][tid & 31];
        if (tid < 4)   mmG[bid * 4 + tid] = mm[tid];
        return;
    }

    // ---- misc: weight decay + smoothness, static fi partition (no per-px branch) ----
    int bid2 = bid - 256;

    // zero the atomic-merge planes + ticket counter (ws is re-poisoned per iter)
    {
        int zi = bid2 * 256 + tid;
        if (zi < 32768)  fi0S[zi] = 0ULL;              // 16*2048
        int z1 = zi;                                    // 16*8192 = 131072 over 262144 threads
        if (z1 < 131072) fi1S[z1] = 0ULL;
        if (zi == 0) *ctr = 0;
    }

    float s = 0.0f;
    // weight decay over all misc blocks
    {
        int gtid = bid2 * 256 + tid;
        const int gstride = MISC_BLOCKS * 256;
        int n4 = nP >> 2;
        const float4* p4 = (const float4*)params;
        float wsum = 0.0f;
        for (int i = gtid; i < n4; i += gstride) {
            float4 v = p4[i];
            wsum += v.x * v.x + v.y * v.y + v.z * v.z + v.w * v.w;
        }
        if (gtid == 0) for (int i = n4 * 4; i < nP; ++i) wsum += params[i] * params[i];
        s += wsum * 5e-5f;
    }

    // smoothness: blocks [0,768)=fi3, [768,960)=fi2, [960,1008)=fi1, [1008,1024)=fi0
    int fi, R, r0;
    if (bid2 < 768)       { fi = 3; R = 768; r0 = 0; }
    else if (bid2 < 960)  { fi = 2; R = 192; r0 = 768; }
    else if (bid2 < 1008) { fi = 1; R = 48;  r0 = 960; }
    else                  { fi = 0; R = 16;  r0 = 1008; }
    const int logW = 5 + fi;
    const int W = 1 << logW;
    const int count = 16 << (2 * logW);     // 8 batches * 2 ch * W * W
    const float* f = (fi == 0) ? f0 : (fi == 1) ? f1 : (fi == 2) ? f2 : f3;
    const float c_lr = 6.25f / (float)(16 * W * (W - 1));
    const float c_dd = 6.25f / (float)(16 * (W - 1) * (W - 1));
    const int g0 = (bid2 - r0) * 256 + tid;
    const int gs = R * 256;

    for (int local = g0; local < count; local += gs) {
        int x = local & (W - 1);
        int y = (local >> logW) & (W - 1);
        float v = f[local];
        bool xok = x < W - 1;
        bool yok = y < W - 1;
        float vr = xok ? f[local + 1] : 0.0f;
        float vd = yok ? f[local + W] : 0.0f;
        if (xok) { float d = vr - v; s += c_lr * pow045(d * d + 1e-6f); }
        if (yok) { float d = vd - v; s += c_lr * pow045(d * d + 1e-6f); }
        if (xok && yok) {
            float d1 = f[local + W + 1] - v;
            s += c_dd * pow045(d1 * d1 + 1e-6f);
            float d2 = vr - vd;
            s += c_dd * pow045(d2 * d2 + 1e-6f);
        }
    }

    for (int o = 32; o > 0; o >>= 1) s += __shfl_down(s, o, 64);
    if ((tid & 63) == 0) red[tid >> 6] = s;
    __syncthreads();
    if (tid == 0) miscP[bid2] = red[0] + red[1] + red[2] + red[3];
}

// =============== pass 2: scatter (blocks 0-255) + binStart/tref/out-zero (256-263) ===============
__global__ __launch_bounds__(256) void k_scatter(
    const int* __restrict__ xs, const int* __restrict__ ys,
    const float* __restrict__ ts, const int* __restrict__ ps,
    const int* __restrict__ histG, const int* __restrict__ mmG,
    uint2* __restrict__ bins, int* __restrict__ binStart,
    float* __restrict__ tref, float* __restrict__ out) {
    int bid = blockIdx.x;
    int tid = threadIdx.x;
    __shared__ int hh[4096];        // histG for this batch: [sl][w][bin] (16 KB)
    __shared__ int curs[4][32];
    __shared__ int binTot[32];
    __shared__ int binBase[32];
    __shared__ int mm[4];

    int b = (bid < 256) ? (bid & 7) : (bid - 256);

    // stage this batch's histograms: histG idx = sl*1024 + b*128 + (w*32+bin)
    for (int i = tid; i < 4096; i += 256)
        hh[i] = histG[(i >> 7) * 1024 + b * 128 + (i & 127)];
    __syncthreads();

    if (bid >= 256) {
        // ---- per-batch binStart + tref; block 256 zeroes out ----
        if (tid < 32) {
            int tot = 0;
            for (int sl2 = 0; sl2 < 32; ++sl2) {
                #pragma unroll
                for (int w2 = 0; w2 < 4; ++w2) tot += hh[sl2 * 128 + w2 * 32 + tid];
            }
            binTot[tid] = tot;
        }
        __syncthreads();
        if (tid == 0) {
            int run = 0;
            for (int k = 0; k < 32; ++k) { binStart[b * 33 + k] = run; run += binTot[k]; }
            binStart[b * 33 + 32] = run;
            if (bid == 256) out[0] = 0.0f;
        }
        if (tid >= 64 && tid < 68) {       // minmax over 32 slice-blocks
            int c = tid - 64;
            int v = (c == 0 || c == 2) ? INT_MAX : -1;
            for (int sl2 = 0; sl2 < 32; ++sl2) {
                int x = mmG[(sl2 * 8 + b) * 4 + c];
                v = (c == 0 || c == 2) ? min(v, x) : max(v, x);
            }
            mm[c] = v;
        }
        __syncthreads();
        if (tid == 64) {
            const float* tb = ts + b * NEV;
            int mnP = mm[0], mxP = mm[1], mnN = mm[2], mxN = mm[3];
            int fP = (mnP == INT_MAX) ? 0 : mnP;
            int lP = (mxP < 0) ? (NEV - 1) : mxP;
            int fN = (mnN == INT_MAX) ? 0 : mnN;
            int lN = (mxN < 0) ? (NEV - 1) : mxN;
            tref[b * 4 + 0] = tb[lP];  // pos fwd
            tref[b * 4 + 1] = tb[fP];  // pos bwd
            tref[b * 4 + 2] = tb[lN];  // neg fwd
            tref[b * 4 + 3] = tb[fN];  // neg bwd
        }
        return;
    }

    // ---- main scatter block: recompute this (sl,b)'s cursors from hh ----
    int sl = bid >> 3;
    if (tid < 128) {
        int w = tid >> 5, bin = tid & 31;
        int pre = 0, tot = 0, wpre = 0;
        for (int sl2 = 0; sl2 < 32; ++sl2) {
            #pragma unroll
            for (int w2 = 0; w2 < 4; ++w2) {
                int v = hh[sl2 * 128 + w2 * 32 + bin];
                tot += v;
                if (sl2 < sl) pre += v;
                if (sl2 == sl && w2 < w) wpre += v;
            }
        }
        if (w == 0) binTot[bin] = tot;
        curs[w][bin] = pre + wpre;        // binBase added after prefix
    }
    __syncthreads();
    if (tid == 0) {
        int run = 0;
        for (int k = 0; k < 32; ++k) { binBase[k] = run; run += binTot[k]; }
    }
    __syncthreads();
    if (tid < 128) curs[tid >> 5][tid & 31] += binBase[tid & 31];
    __syncthreads();

    const int*   xb = xs + b * NEV + sl * SLEV;
    const int*   yb = ys + b * NEV + sl * SLEV;
    const float* tb = ts + b * NEV + sl * SLEV;
    const int*   pb = ps + b * NEV + sl * SLEV;
    uint2* ob = bins + b * NEV;
    int w = tid >> 6, lane = tid & 63;

    for (int i = w * 64 + lane; i < SLEV; i += 256) {
        int p = pb[i];
        int x = xb[i];
        int y = yb[i];
        float t = tb[i];
        int m = (p == 1) ? 0 : 1;
        int bin = m * 16 + (y >> 4);
        int pos = lds_add32(&curs[w][bin], 1);
        ob[pos] = make_uint2((unsigned)(x | (y << 8)), __float_as_uint(t));
    }
}

// =============== event splat: 512 blocks = 2/CU; merge folded into last mode-0 block ===============
__global__ __launch_bounds__(1024) void k_splat(
    const float* __restrict__ f0, const float* __restrict__ f1,
    const float* __restrict__ f2, const float* __restrict__ f3,
    const uint2* __restrict__ bins, const int* __restrict__ binStart,
    const float* __restrict__ tref,
    u64* __restrict__ fi0S, u64* __restrict__ fi1S,
    const float* __restrict__ miscP, int* __restrict__ ctr,
    float* __restrict__ out) {
    __shared__ u64 acc[8192];   // 64 KB
    __shared__ float red[16];
    __shared__ int shT;

    int tid = threadIdx.x;
    int bid = blockIdx.x;
    int b = bid & 7;
    int rm = bid >> 3;          // 0..63
    int m = rm & 1;
    int role = rm >> 1;         // 0..31
    int bm = b * 2 + m;

    int fi, row0 = 0, nrows, lo, hi, slice = 0, nslice = 1, mode;
    if (role < 4)       { fi = 0; mode = 0; slice = role;     nslice = 4; nrows = 32; lo = 0; hi = 15; }
    else if (role < 8)  { fi = 1; mode = 0; slice = role - 4; nslice = 4; nrows = 64; lo = 0; hi = 15; }
    else if (role < 16) { int c = role - 8;  fi = 2; mode = 1; row0 = 16 * c; nrows = 16;
                          lo = max(0, 2 * c - 1); hi = min(15, 2 * c + 2); }
    else                { int c = role - 16; fi = 3; mode = 1; row0 = 16 * c; nrows = 16;
                          lo = max(0, c - 1); hi = min(15, c + 1); }

    int W = 32 << fi;
    int sh = 3 - fi;
    int planeN = (fi == 0) ? 1024 : (fi == 1) ? 4096 : nrows * W;
    int used = (fi == 0) ? 8192 : 2 * planeN;
    int rowEnd = row0 + nrows;
    float Wm1 = (float)(W - 1);

    const float* flow = (fi == 0) ? f0 : (fi == 1) ? f1 : (fi == 2) ? f2 : f3;
    const float* fxp = flow + (size_t)b * 2 * W * W;
    const float* fyp = fxp + W * W;

    for (int i = tid; i < used; i += 1024) acc[i] = 0ULL;
    __syncthreads();

    float trF = tref[b * 4 + m * 2 + 0];
    float trB = tref[b * 4 + m * 2 + 1];

    int s0 = binStart[b * 33 + m * 16 + lo];
    int e0 = binStart[b * 33 + m * 16 + hi + 1];
    const uint2* eb = bins + b * NEV;

    int rep = (fi == 0) ? (((tid >> 4) & 3) * 2048) : 0;

    for (int i = s0 + slice * 1024 + tid; i < e0; i += nslice * 1024) {
        uint2 ev = eb[i];
        int x = ev.x & 255;
        int y = (ev.x >> 8) & 255;
        float t = __uint_as_float(ev.y);
        int xi = x >> sh, yi = y >> sh;
        float fx = fxp[yi * W + xi];
        float fy = fyp[yi * W + xi];
        float tF = trF - t + F32EPS;
        float tB = trB - t - F32EPS;
        #pragma unroll
        for (int dir = 0; dir < 2; ++dir) {
            float t_ = dir ? tB : tF;
            float x_ = fminf(fmaxf((float)xi + t_ * fx, 0.0f), Wm1);
            float y_ = fminf(fmaxf((float)yi + t_ * fy, 0.0f), Wm1);
            float x0f = floorf(x_), y0f = floorf(y_);
            float x0w = x_ - x0f, x1w = 1.0f - x0w;
            float y0w = y_ - y0f, y1w = 1.0f - y0w;
            int x0i = (int)x0f, y0i = (int)y0f;
            int x1i = min(x0i + 1, W - 1);
            int y1i = min(y0i + 1, W - 1);
            u64 Pa = (1ULL << 32) | (u64)(unsigned)(x0w * y0w * t * SCALE);
            u64 Pb = (1ULL << 32) | (u64)(unsigned)(x1w * y0w * t * SCALE);
            u64 Pc = (1ULL << 32) | (u64)(unsigned)(x0w * y1w * t * SCALE);
            u64 Pd = (1ULL << 32) | (u64)(unsigned)(x1w * y1w * t * SCALE);
            int base = rep + dir * planeN;
            if (mode == 0) {
                int r1 = base + y1i * W;
                int r0 = base + y0i * W;
                lds_add64(&acc[r1 + x1i], Pa);
                lds_add64(&acc[r1 + x0i], Pb);
                lds_add64(&acc[r0 + x1i], Pc);
                lds_add64(&acc[r0 + x0i], Pd);
            } else {
                if (y1i >= row0 && y1i < rowEnd) {
                    int r = base + (y1i - row0) * W;
                    lds_add64(&acc[r + x1i], Pa);
                    lds_add64(&acc[r + x0i], Pb);
                }
                if (y0i >= row0 && y0i < rowEnd) {
                    int r = base + (y0i - row0) * W;
                    lds_add64(&acc[r + x1i], Pc);
                    lds_add64(&acc[r + x0i], Pd);
                }
            }
        }
    }
    __syncthreads();

    if (mode == 0) {
        // accumulate into the shared plane via device atomics (planes zeroed in k_front)
        if (fi == 0) {
            u64* plane = fi0S + bm * 2048;
            for (int j = tid; j < 2048; j += 1024) {
                u64 v = acc[j] + acc[j + 2048] + acc[j + 4096] + acc[j + 6144];
                if (v) atomicAdd(&plane[j], v);
            }
        } else {
            u64* plane = fi1S + bm * 8192;
            for (int j = tid; j < 8192; j += 1024) {
                u64 v = acc[j];
                if (v) atomicAdd(&plane[j], v);
            }
        }
        // ticket among the 128 mode-0 blocks; last one merges (runs concurrent
        // with still-executing mode-1 blocks on other CUs)
        __syncthreads();
        if (tid == 0) {
            __threadfence();
            shT = atomicAdd(ctr, 1);
        }
        __syncthreads();
        if (shT == 127) {
            __threadfence();
            float s = miscP[tid];            // fold misc partials (1024 entries)
            for (int idx = tid; idx < 163840; idx += 1024) {
                u64 v = (idx < 32768) ? fi0S[idx] : fi1S[idx - 32768];
                float num = (float)(unsigned)(v & 0xffffffffULL) * INV_SCALE;
                float den = (float)(unsigned)(v >> 32);
                float r = num / (den + F32EPS);
                s += sqrtf(r * r + 1e-6f);
            }
            for (int o = 32; o > 0; o >>= 1) s += __shfl_down(s, o, 64);
            if ((tid & 63) == 0) red[tid >> 6] = s;
            __syncthreads();
            if (tid == 0) {
                float tot = 0.0f;
                for (int w2 = 0; w2 < 16; ++w2) tot += red[w2];
                atomicAdd(out, tot);
            }
        }
        return;
    }

    float s = 0.0f;
    for (int j = tid; j < used; j += 1024) {
        u64 v = acc[j];
        float num = (float)(unsigned)(v & 0xffffffffULL) * INV_SCALE;
        float den = (float)(unsigned)(v >> 32);
        float r = num / (den + F32EPS);
        s += sqrtf(r * r + 1e-6f);
    }
    for (int o = 32; o > 0; o >>= 1) s += __shfl_down(s, o, 64);
    if ((tid & 63) == 0) red[tid >> 6] = s;
    __syncthreads();
    if (tid == 0) {
        float tot = 0.0f;
        for (int w2 = 0; w2 < 16; ++w2) tot += red[w2];
        atomicAdd(out, tot);
    }
}

extern "C" void kernel_launch(void* const* d_in, const int* in_sizes, int n_in,
                              void* d_out, int out_size, void* d_ws, size_t ws_size,
                              hipStream_t stream) {
    const float* f0 = (const float*)d_in[0];
    const float* f1 = (const float*)d_in[1];
    const float* f2 = (const float*)d_in[2];
    const float* f3 = (const float*)d_in[3];
    const int*   xs = (const int*)d_in[4];
    const int*   ys = (const int*)d_in[5];
    const float* ts = (const float*)d_in[6];
    const int*   ps = (const int*)d_in[7];
    const float* params = (const float*)d_in[10];
    float* out = (float*)d_out;

    char* ws = (char*)d_ws;
    uint2* bins     = (uint2*)ws;
    int*   binStart = (int*)(ws + OFF_BINSTART);
    float* tref     = (float*)(ws + OFF_TREF);
    u64*   fi0S     = (u64*)(ws + OFF_FI0S);
    u64*   fi1S     = (u64*)(ws + OFF_FI1S);
    int*   histG    = (int*)(ws + OFF_HISTG);
    int*   mmG      = (int*)(ws + OFF_MMG);
    float* miscP    = (float*)(ws + OFF_MISCP);
    int*   ctr      = (int*)(ws + OFF_CTR);

    hipLaunchKernelGGL(k_front, dim3(256 + MISC_BLOCKS), dim3(256), 0, stream,
                       ys, ps, params, in_sizes[10], f0, f1, f2, f3,
                       histG, mmG, miscP, fi0S, fi1S, ctr);
    hipLaunchKernelGGL(k_scatter, dim3(264), dim3(256), 0, stream,
                       xs, ys, ts, ps, histG, mmG, bins, binStart, tref, out);
    hipLaunchKernelGGL(k_splat, dim3(512), dim3(1024), 0, stream,
                       f0, f1, f2, f3, bins, binStart, tref,
                       fi0S, fi1S, miscP, ctr, out);
}

// Round 8
// 148.389 us; speedup vs baseline: 1.4115x; 1.4115x over previous
//
#include <hip/hip_runtime.h>
#include <math.h>
#include <limits.h>

#define NEV 100000
#define NB 8
#define NSL 32                   // slices per batch
#define SLEV (NEV / NSL)         // 3125 events per slice
#define F32EPS 1.1920929e-7f
#define SCALE 524288.0f          // 2^19 fixed-point for num
#define INV_SCALE (1.0f/524288.0f)

typedef unsigned long long u64;

// ws layout (bytes):
//   0          bins: uint2[8][NEV]                 6,400,000
//   6,400,000  binStart: int[8][33]                1,056
//   6,401,056  tref: float[32]                     128
//   6,401,184  fi0P: u64[16][4][2048]              1,048,576
//   7,449,760  fi1P: u64[16][4][8192]              4,194,304
//   11,644,064 histG: int[256][4][32]              131,072
//   11,775,136 mmG:   int[256][4]                  4,096
//   11,779,232 miscP: float[1024]                  4,096
#define OFF_BINSTART 6400000
#define OFF_TREF     6401056
#define OFF_FI0P     6401184
#define OFF_FI1P     7449760
#define OFF_HISTG    11644064
#define OFF_MMG      11775136
#define OFF_MISCP    11779232

#define MISC_BLOCKS 1024

__device__ __forceinline__ void lds_add64(u64* p, u64 v) {
    __hip_atomic_fetch_add(p, v, __ATOMIC_RELAXED, __HIP_MEMORY_SCOPE_WORKGROUP);
}
__device__ __forceinline__ int lds_add32(int* p, int v) {
    return __hip_atomic_fetch_add(p, v, __ATOMIC_RELAXED, __HIP_MEMORY_SCOPE_WORKGROUP);
}

// fast z^0.45 for z > 0: v_log_f32 (log2) + v_mul + v_exp_f32 (2^x) — 3 ops.
// (__powf lowers to the full OCML pow path; R6 confirmed −14 us from this.)
__device__ __forceinline__ float pow045(float z) {
    return __builtin_amdgcn_exp2f(0.45f * __builtin_amdgcn_logf(z));
}

// =============== pass 1: hist (blocks 0-255) PARALLEL misc (blocks 256-1279) ===============
// R7 lesson: keep partial-plane stores + separate merge kernel; global atomic
// merge in-splat cost ~60us of L2 RMW contention (same-address lockstep).
__global__ __launch_bounds__(256) void k_front(
    const int* __restrict__ ys, const int* __restrict__ ps,
    const float* __restrict__ params, int nP,
    const float* __restrict__ f0, const float* __restrict__ f1,
    const float* __restrict__ f2, const float* __restrict__ f3,
    int* __restrict__ histG, int* __restrict__ mmG, float* __restrict__ miscP) {
    int tid = threadIdx.x;
    int bid = blockIdx.x;
    __shared__ int hist[4][32];
    __shared__ int mm[4];
    __shared__ float red[4];

    if (bid < 256) {
        // ---- histogram + minmax for (slice, batch) ----
        int b = bid & 7;
        int sl = bid >> 3;
        int w = tid >> 6, lane = tid & 63;
        const int* yb = ys + b * NEV + sl * SLEV;
        const int* pb = ps + b * NEV + sl * SLEV;

        if (tid < 128) hist[tid >> 5][tid & 31] = 0;
        if (tid == 0) { mm[0] = INT_MAX; mm[1] = -1; mm[2] = INT_MAX; mm[3] = -1; }
        __syncthreads();

        int mnP = INT_MAX, mxP = -1, mnN = INT_MAX, mxN = -1;
        int gbase = sl * SLEV;
        for (int i = w * 64 + lane; i < SLEV; i += 256) {
            int p = pb[i];
            int y = yb[i];
            int m = (p == 1) ? 0 : 1;
            lds_add32(&hist[w][m * 16 + (y >> 4)], 1);
            int gi = gbase + i;
            if (m == 0) { mnP = min(mnP, gi); mxP = max(mxP, gi); }
            else        { mnN = min(mnN, gi); mxN = max(mxN, gi); }
        }
        for (int o = 32; o > 0; o >>= 1) {
            mnP = min(mnP, __shfl_down(mnP, o, 64));
            mxP = max(mxP, __shfl_down(mxP, o, 64));
            mnN = min(mnN, __shfl_down(mnN, o, 64));
            mxN = max(mxN, __shfl_down(mxN, o, 64));
        }
        if (lane == 0) {
            atomicMin(&mm[0], mnP); atomicMax(&mm[1], mxP);
            atomicMin(&mm[2], mnN); atomicMax(&mm[3], mxN);
        }
        __syncthreads();
        if (tid < 128) histG[(bid * 4 + (tid >> 5)) * 32 + (tid & 31)] = hist[tid >> 5][tid & 31];
        if (tid < 4)   mmG[bid * 4 + tid] = mm[tid];
        return;
    }

    // ---- misc: weight decay + smoothness, static fi partition (no per-px branch) ----
    int bid2 = bid - 256;
    float s = 0.0f;

    // weight decay over all misc blocks
    {
        int gtid = bid2 * 256 + tid;
        const int gstride = MISC_BLOCKS * 256;
        int n4 = nP >> 2;
        const float4* p4 = (const float4*)params;
        float wsum = 0.0f;
        for (int i = gtid; i < n4; i += gstride) {
            float4 v = p4[i];
            wsum += v.x * v.x + v.y * v.y + v.z * v.z + v.w * v.w;
        }
        if (gtid == 0) for (int i = n4 * 4; i < nP; ++i) wsum += params[i] * params[i];
        s += wsum * 5e-5f;
    }

    // smoothness: blocks [0,768)=fi3, [768,960)=fi2, [960,1008)=fi1, [1008,1024)=fi0
    int fi, R, r0;
    if (bid2 < 768)       { fi = 3; R = 768; r0 = 0; }
    else if (bid2 < 960)  { fi = 2; R = 192; r0 = 768; }
    else if (bid2 < 1008) { fi = 1; R = 48;  r0 = 960; }
    else                  { fi = 0; R = 16;  r0 = 1008; }
    const int logW = 5 + fi;
    const int W = 1 << logW;
    const int count = 16 << (2 * logW);     // 8 batches * 2 ch * W * W
    const float* f = (fi == 0) ? f0 : (fi == 1) ? f1 : (fi == 2) ? f2 : f3;
    const float c_lr = 6.25f / (float)(16 * W * (W - 1));
    const float c_dd = 6.25f / (float)(16 * (W - 1) * (W - 1));
    const int g0 = (bid2 - r0) * 256 + tid;
    const int gs = R * 256;

    for (int local = g0; local < count; local += gs) {
        int x = local & (W - 1);
        int y = (local >> logW) & (W - 1);
        float v = f[local];
        bool xok = x < W - 1;
        bool yok = y < W - 1;
        float vr = xok ? f[local + 1] : 0.0f;
        float vd = yok ? f[local + W] : 0.0f;
        if (xok) { float d = vr - v; s += c_lr * pow045(d * d + 1e-6f); }
        if (yok) { float d = vd - v; s += c_lr * pow045(d * d + 1e-6f); }
        if (xok && yok) {
            float d1 = f[local + W + 1] - v;
            s += c_dd * pow045(d1 * d1 + 1e-6f);
            float d2 = vr - vd;
            s += c_dd * pow045(d2 * d2 + 1e-6f);
        }
    }

    for (int o = 32; o > 0; o >>= 1) s += __shfl_down(s, o, 64);
    if ((tid & 63) == 0) red[tid >> 6] = s;
    __syncthreads();
    if (tid == 0) miscP[bid2] = red[0] + red[1] + red[2] + red[3];
}

// =============== pass 2: scatter (blocks 0-255) + binStart/tref/out-zero (256-263) ===============
__global__ __launch_bounds__(256) void k_scatter(
    const int* __restrict__ xs, const int* __restrict__ ys,
    const float* __restrict__ ts, const int* __restrict__ ps,
    const int* __restrict__ histG, const int* __restrict__ mmG,
    uint2* __restrict__ bins, int* __restrict__ binStart,
    float* __restrict__ tref, float* __restrict__ out) {
    int bid = blockIdx.x;
    int tid = threadIdx.x;
    __shared__ int hh[4096];        // histG for this batch: [sl][w][bin] (16 KB)
    __shared__ int curs[4][32];
    __shared__ int binTot[32];
    __shared__ int binBase[32];
    __shared__ int mm[4];

    int b = (bid < 256) ? (bid & 7) : (bid - 256);

    // stage this batch's histograms: histG idx = sl*1024 + b*128 + (w*32+bin)
    for (int i = tid; i < 4096; i += 256)
        hh[i] = histG[(i >> 7) * 1024 + b * 128 + (i & 127)];
    __syncthreads();

    if (bid >= 256) {
        // ---- per-batch binStart + tref; block 256 zeroes out ----
        if (tid < 32) {
            int tot = 0;
            for (int sl2 = 0; sl2 < 32; ++sl2) {
                #pragma unroll
                for (int w2 = 0; w2 < 4; ++w2) tot += hh[sl2 * 128 + w2 * 32 + tid];
            }
            binTot[tid] = tot;
        }
        __syncthreads();
        if (tid == 0) {
            int run = 0;
            for (int k = 0; k < 32; ++k) { binStart[b * 33 + k] = run; run += binTot[k]; }
            binStart[b * 33 + 32] = run;
            if (bid == 256) out[0] = 0.0f;
        }
        if (tid >= 64 && tid < 68) {       // minmax over 32 slice-blocks
            int c = tid - 64;
            int v = (c == 0 || c == 2) ? INT_MAX : -1;
            for (int sl2 = 0; sl2 < 32; ++sl2) {
                int x = mmG[(sl2 * 8 + b) * 4 + c];
                v = (c == 0 || c == 2) ? min(v, x) : max(v, x);
            }
            mm[c] = v;
        }
        __syncthreads();
        if (tid == 64) {
            const float* tb = ts + b * NEV;
            int mnP = mm[0], mxP = mm[1], mnN = mm[2], mxN = mm[3];
            int fP = (mnP == INT_MAX) ? 0 : mnP;
            int lP = (mxP < 0) ? (NEV - 1) : mxP;
            int fN = (mnN == INT_MAX) ? 0 : mnN;
            int lN = (mxN < 0) ? (NEV - 1) : mxN;
            tref[b * 4 + 0] = tb[lP];  // pos fwd
            tref[b * 4 + 1] = tb[fP];  // pos bwd
            tref[b * 4 + 2] = tb[lN];  // neg fwd
            tref[b * 4 + 3] = tb[fN];  // neg bwd
        }
        return;
    }

    // ---- main scatter block: recompute this (sl,b)'s cursors from hh ----
    int sl = bid >> 3;
    if (tid < 128) {
        int w = tid >> 5, bin = tid & 31;
        int pre = 0, tot = 0, wpre = 0;
        for (int sl2 = 0; sl2 < 32; ++sl2) {
            #pragma unroll
            for (int w2 = 0; w2 < 4; ++w2) {
                int v = hh[sl2 * 128 + w2 * 32 + bin];
                tot += v;
                if (sl2 < sl) pre += v;
                if (sl2 == sl && w2 < w) wpre += v;
            }
        }
        if (w == 0) binTot[bin] = tot;
        curs[w][bin] = pre + wpre;        // binBase added after prefix
    }
    __syncthreads();
    if (tid == 0) {
        int run = 0;
        for (int k = 0; k < 32; ++k) { binBase[k] = run; run += binTot[k]; }
    }
    __syncthreads();
    if (tid < 128) curs[tid >> 5][tid & 31] += binBase[tid & 31];
    __syncthreads();

    const int*   xb = xs + b * NEV + sl * SLEV;
    const int*   yb = ys + b * NEV + sl * SLEV;
    const float* tb = ts + b * NEV + sl * SLEV;
    const int*   pb = ps + b * NEV + sl * SLEV;
    uint2* ob = bins + b * NEV;
    int w = tid >> 6, lane = tid & 63;

    for (int i = w * 64 + lane; i < SLEV; i += 256) {
        int p = pb[i];
        int x = xb[i];
        int y = yb[i];
        float t = tb[i];
        int m = (p == 1) ? 0 : 1;
        int bin = m * 16 + (y >> 4);
        int pos = lds_add32(&curs[w][bin], 1);
        ob[pos] = make_uint2((unsigned)(x | (y << 8)), __float_as_uint(t));
    }
}

// =============== event splat: 512 blocks = exactly 2/CU, no tail ===============
__global__ __launch_bounds__(1024) void k_splat(
    const float* __restrict__ f0, const float* __restrict__ f1,
    const float* __restrict__ f2, const float* __restrict__ f3,
    const uint2* __restrict__ bins, const int* __restrict__ binStart,
    const float* __restrict__ tref,
    u64* __restrict__ fi0P, u64* __restrict__ fi1P,
    float* __restrict__ out) {
    __shared__ u64 acc[8192];   // 64 KB
    __shared__ float red[16];

    int tid = threadIdx.x;
    int bid = blockIdx.x;
    int b = bid & 7;
    int rm = bid >> 3;          // 0..63
    int m = rm & 1;
    int role = rm >> 1;         // 0..31
    int bm = b * 2 + m;

    int fi, row0 = 0, nrows, lo, hi, slice = 0, nslice = 1, mode;
    if (role < 4)       { fi = 0; mode = 0; slice = role;     nslice = 4; nrows = 32; lo = 0; hi = 15; }
    else if (role < 8)  { fi = 1; mode = 0; slice = role - 4; nslice = 4; nrows = 64; lo = 0; hi = 15; }
    else if (role < 16) { int c = role - 8;  fi = 2; mode = 1; row0 = 16 * c; nrows = 16;
                          lo = max(0, 2 * c - 1); hi = min(15, 2 * c + 2); }
    else                { int c = role - 16; fi = 3; mode = 1; row0 = 16 * c; nrows = 16;
                          lo = max(0, c - 1); hi = min(15, c + 1); }

    int W = 32 << fi;
    int sh = 3 - fi;
    int planeN = (fi == 0) ? 1024 : (fi == 1) ? 4096 : nrows * W;
    int used = (fi == 0) ? 8192 : 2 * planeN;
    int rowEnd = row0 + nrows;
    float Wm1 = (float)(W - 1);

    const float* flow = (fi == 0) ? f0 : (fi == 1) ? f1 : (fi == 2) ? f2 : f3;
    const float* fxp = flow + (size_t)b * 2 * W * W;
    const float* fyp = fxp + W * W;

    for (int i = tid; i < used; i += 1024) acc[i] = 0ULL;
    __syncthreads();

    float trF = tref[b * 4 + m * 2 + 0];
    float trB = tref[b * 4 + m * 2 + 1];

    int s0 = binStart[b * 33 + m * 16 + lo];
    int e0 = binStart[b * 33 + m * 16 + hi + 1];
    const uint2* eb = bins + b * NEV;

    int rep = (fi == 0) ? (((tid >> 4) & 3) * 2048) : 0;

    for (int i = s0 + slice * 1024 + tid; i < e0; i += nslice * 1024) {
        uint2 ev = eb[i];
        int x = ev.x & 255;
        int y = (ev.x >> 8) & 255;
        float t = __uint_as_float(ev.y);
        int xi = x >> sh, yi = y >> sh;
        float fx = fxp[yi * W + xi];
        float fy = fyp[yi * W + xi];
        float tF = trF - t + F32EPS;
        float tB = trB - t - F32EPS;
        #pragma unroll
        for (int dir = 0; dir < 2; ++dir) {
            float t_ = dir ? tB : tF;
            float x_ = fminf(fmaxf((float)xi + t_ * fx, 0.0f), Wm1);
            float y_ = fminf(fmaxf((float)yi + t_ * fy, 0.0f), Wm1);
            float x0f = floorf(x_), y0f = floorf(y_);
            float x0w = x_ - x0f, x1w = 1.0f - x0w;
            float y0w = y_ - y0f, y1w = 1.0f - y0w;
            int x0i = (int)x0f, y0i = (int)y0f;
            int x1i = min(x0i + 1, W - 1);
            int y1i = min(y0i + 1, W - 1);
            u64 Pa = (1ULL << 32) | (u64)(unsigned)(x0w * y0w * t * SCALE);
            u64 Pb = (1ULL << 32) | (u64)(unsigned)(x1w * y0w * t * SCALE);
            u64 Pc = (1ULL << 32) | (u64)(unsigned)(x0w * y1w * t * SCALE);
            u64 Pd = (1ULL << 32) | (u64)(unsigned)(x1w * y1w * t * SCALE);
            int base = rep + dir * planeN;
            if (mode == 0) {
                int r1 = base + y1i * W;
                int r0 = base + y0i * W;
                lds_add64(&acc[r1 + x1i], Pa);
                lds_add64(&acc[r1 + x0i], Pb);
                lds_add64(&acc[r0 + x1i], Pc);
                lds_add64(&acc[r0 + x0i], Pd);
            } else {
                if (y1i >= row0 && y1i < rowEnd) {
                    int r = base + (y1i - row0) * W;
                    lds_add64(&acc[r + x1i], Pa);
                    lds_add64(&acc[r + x0i], Pb);
                }
                if (y0i >= row0 && y0i < rowEnd) {
                    int r = base + (y0i - row0) * W;
                    lds_add64(&acc[r + x1i], Pc);
                    lds_add64(&acc[r + x0i], Pd);
                }
            }
        }
    }
    __syncthreads();

    if (mode == 0) {
        if (fi == 0) {
            for (int j = tid; j < 2048; j += 1024)
                fi0P[(bm * 4 + slice) * 2048 + j] =
                    acc[j] + acc[j + 2048] + acc[j + 4096] + acc[j + 6144];
        } else {
            for (int j = tid; j < 8192; j += 1024)
                fi1P[(bm * 4 + slice) * 8192 + j] = acc[j];
        }
        return;
    }

    float s = 0.0f;
    for (int j = tid; j < used; j += 1024) {
        u64 v = acc[j];
        float num = (float)(unsigned)(v & 0xffffffffULL) * INV_SCALE;
        float den = (float)(unsigned)(v >> 32);
        float r = num / (den + F32EPS);
        s += sqrtf(r * r + 1e-6f);
    }
    for (int o = 32; o > 0; o >>= 1) s += __shfl_down(s, o, 64);
    if ((tid & 63) == 0) red[tid >> 6] = s;
    __syncthreads();
    if (tid == 0) {
        float tot = 0.0f;
        for (int w2 = 0; w2 < 16; ++w2) tot += red[w2];
        atomicAdd(out, tot);
    }
}

// =============== merge fi0/fi1 partials + misc partials -> loss terms ===============
__global__ __launch_bounds__(256) void k_merge(const u64* __restrict__ fi0P,
                                               const u64* __restrict__ fi1P,
                                               const float* __restrict__ miscP,
                                               float* __restrict__ out) {
    int idx = blockIdx.x * 256 + threadIdx.x;   // < 163840
    u64 v = 0;
    if (idx < 32768) {
        int bm = idx >> 11, j = idx & 2047;
        const u64* p = fi0P + (bm * 4) * 2048 + j;
        #pragma unroll
        for (int s = 0; s < 4; ++s) v += p[s * 2048];
    } else {
        int r = idx - 32768;
        int bm = r >> 13, j = r & 8191;
        const u64* p = fi1P + (bm * 4) * 8192 + j;
        #pragma unroll
        for (int s = 0; s < 4; ++s) v += p[s * 8192];
    }
    float num = (float)(unsigned)(v & 0xffffffffULL) * INV_SCALE;
    float den = (float)(unsigned)(v >> 32);
    float r = num / (den + F32EPS);
    float s = sqrtf(r * r + 1e-6f);

    // fold in misc partials (block 0 only): add per-thread before reduction
    if (blockIdx.x == 0) {
        float ms = miscP[threadIdx.x] + miscP[threadIdx.x + 256]
                 + miscP[threadIdx.x + 512] + miscP[threadIdx.x + 768];
        s += ms;
    }

    for (int o = 32; o > 0; o >>= 1) s += __shfl_down(s, o, 64);
    __shared__ float red[4];
    if ((threadIdx.x & 63) == 0) red[threadIdx.x >> 6] = s;
    __syncthreads();
    if (threadIdx.x == 0)
        atomicAdd(out, red[0] + red[1] + red[2] + red[3]);
}

extern "C" void kernel_launch(void* const* d_in, const int* in_sizes, int n_in,
                              void* d_out, int out_size, void* d_ws, size_t ws_size,
                              hipStream_t stream) {
    const float* f0 = (const float*)d_in[0];
    const float* f1 = (const float*)d_in[1];
    const float* f2 = (const float*)d_in[2];
    const float* f3 = (const float*)d_in[3];
    const int*   xs = (const int*)d_in[4];
    const int*   ys = (const int*)d_in[5];
    const float* ts = (const float*)d_in[6];
    const int*   ps = (const int*)d_in[7];
    const float* params = (const float*)d_in[10];
    float* out = (float*)d_out;

    char* ws = (char*)d_ws;
    uint2* bins     = (uint2*)ws;
    int*   binStart = (int*)(ws + OFF_BINSTART);
    float* tref     = (float*)(ws + OFF_TREF);
    u64*   fi0P     = (u64*)(ws + OFF_FI0P);
    u64*   fi1P     = (u64*)(ws + OFF_FI1P);
    int*   histG    = (int*)(ws + OFF_HISTG);
    int*   mmG      = (int*)(ws + OFF_MMG);
    float* miscP    = (float*)(ws + OFF_MISCP);

    hipLaunchKernelGGL(k_front, dim3(256 + MISC_BLOCKS), dim3(256), 0, stream,
                       ys, ps, params, in_sizes[10], f0, f1, f2, f3, histG, mmG, miscP);
    hipLaunchKernelGGL(k_scatter, dim3(264), dim3(256), 0, stream,
                       xs, ys, ts, ps, histG, mmG, bins, binStart, tref, out);
    hipLaunchKernelGGL(k_splat, dim3(512), dim3(1024), 0, stream,
                       f0, f1, f2, f3, bins, binStart, tref, fi0P, fi1P, out);
    hipLaunchKernelGGL(k_merge, dim3(640), dim3(256), 0, stream, fi0P, fi1P, miscP, out);
}